// Round 13
// baseline (117.311 us; speedup 1.0000x reference)
//
#include <hip/hip_runtime.h>
#include <stdint.h>

#define LEN 512
#define NB 64
#define NCX 64
#define NCV 4
#define NCU 4

typedef float f4 __attribute__((ext_vector_type(4)));

// ---------------- Threefry-2x32, 20 rounds, key = (0, 42) ----------------
__device__ __forceinline__ uint32_t rotl32(uint32_t v, int r) {
  return (v << r) | (v >> (32 - r));
}

__device__ __forceinline__ void threefry2x32_k042(uint32_t c0, uint32_t c1,
                                                  uint32_t& o0, uint32_t& o1) {
  const uint32_t ks0 = 0u, ks1 = 42u;
  const uint32_t ks2 = 0u ^ 42u ^ 0x1BD11BDAu;
  uint32_t x0 = c0 + ks0;
  uint32_t x1 = c1 + ks1;
#define TF_ROUND(R) { x0 += x1; x1 = rotl32(x1, R); x1 ^= x0; }
  TF_ROUND(13) TF_ROUND(15) TF_ROUND(26) TF_ROUND(6)
  x0 += ks1; x1 += ks2 + 1u;
  TF_ROUND(17) TF_ROUND(29) TF_ROUND(16) TF_ROUND(24)
  x0 += ks2; x1 += ks0 + 2u;
  TF_ROUND(13) TF_ROUND(15) TF_ROUND(26) TF_ROUND(6)
  x0 += ks0; x1 += ks1 + 3u;
  TF_ROUND(17) TF_ROUND(29) TF_ROUND(16) TF_ROUND(24)
  x0 += ks1; x1 += ks2 + 4u;
  TF_ROUND(13) TF_ROUND(15) TF_ROUND(26) TF_ROUND(6)
  x0 += ks2; x1 += ks0 + 5u;
#undef TF_ROUND
  o0 = x0; o1 = x1;
}

// ---------------- Kernel 1: permutation (fwd + inverse), ml, mask_p -------
// (unchanged from R9: packed-key rank, uint4 LDS scan)
__global__ __launch_bounds__(LEN) void build_perm(const void* __restrict__ mask,
                                                  int* __restrict__ src,
                                                  int* __restrict__ dst,
                                                  int* __restrict__ ml_arr,
                                                  float* __restrict__ mask_out) {
  const int b = blockIdx.x;
  const int l = threadIdx.x;
  const int wave = l >> 6, lane = l & 63;
  __shared__ alignas(16) uint32_t s_pack[LEN];
  __shared__ int wsum[8];
  __shared__ int woff[9];

  const uint32_t w0 = ((const uint32_t*)mask)[0];
  bool valid;
  if (w0 == 1u) {
    valid = ((const int*)mask)[b * LEN + l] != 0;
  } else if (w0 == 0x3F800000u) {
    valid = ((const float*)mask)[b * LEN + l] != 0.0f;
  } else {
    valid = ((const unsigned char*)mask)[b * LEN + l] != 0;
  }
  const bool inv = !valid;

  uint32_t o0, o1;
  threefry2x32_k042(0u, (uint32_t)(b * LEN + l), o0, o1);
  const uint32_t bits = o0 ^ o1;
  const uint32_t ui = (bits >> 9) | 0x3F800000u;
  const uint32_t me = ((ui & 0x7FFFFFu) << 9) | (uint32_t)(511 - l);

  const unsigned long long bal = __ballot(inv);
  const int lower = __popcll(bal & ((1ull << lane) - 1ull));
  if (lane == 0) wsum[wave] = __popcll(bal);
  __syncthreads();
  if (l == 0) {
    int acc = 0;
    for (int w = 0; w < 8; ++w) { woff[w] = acc; acc += wsum[w]; }
    woff[8] = acc;
  }
  __syncthreads();
  const int n_inv = woff[8];
  const int inv_before = woff[wave] + lower;
  if (inv) {
    s_pack[inv_before] = me;
  }
  __syncthreads();

  int pos;
  if (inv) {
    int rank = 0;
    int j = 0;
    for (; j + 8 <= n_inv; j += 8) {
      const uint4 p0 = *(const uint4*)&s_pack[j];
      const uint4 p1 = *(const uint4*)&s_pack[j + 4];
      rank += (int)(p0.x > me) + (int)(p0.y > me) + (int)(p0.z > me) +
              (int)(p0.w > me) + (int)(p1.x > me) + (int)(p1.y > me) +
              (int)(p1.z > me) + (int)(p1.w > me);
    }
    for (; j < n_inv; ++j) rank += (int)(s_pack[j] > me);
    pos = rank;
  } else {
    pos = n_inv + (l - inv_before);
  }
  src[b * LEN + pos] = l;
  dst[b * LEN + l] = pos;

  const int nv = LEN - n_inv;
  const int ml = nv < 1 ? 1 : nv;
  if (l == 0) ml_arr[b] = ml;
  mask_out[b * LEN + l] = (l >= n_inv && l < ml) ? 1.0f : 0.0f;
}

// ---- async global->LDS, 16B per lane, dest = base + lane*16 ----
__device__ __forceinline__ void gload16(const float* g, float* l) {
  __builtin_amdgcn_global_load_lds(
      (const __attribute__((address_space(1))) void*)g,
      (__attribute__((address_space(3))) void*)l, 16, 0, 0);
}

// ---------------- Kernel 2: uu + fused x/v gather ----------------
// Direction B (dense sequential writes), rows staged via global_load_lds
// (no VGPR round-trip, ~60 VGPR -> 8 waves/SIMD). Triple-buffered wave-
// private slots; hand-counted s_waitcnt vmcnt(N) (in-order retirement:
// steady state vmcnt(8), never 0) keeps 3 rows of loads in flight with
// ZERO barriers. Each row = two dense 1KB segments (lane*16B).
__global__ __launch_bounds__(256) void uu_perm(const float* __restrict__ in,
                                               float* __restrict__ out,
                                               const float* __restrict__ xin,
                                               const float* __restrict__ vin,
                                               float* __restrict__ xout,
                                               float* __restrict__ vout,
                                               const int* __restrict__ src,
                                               const int* __restrict__ ml_arr) {
  __shared__ alignas(16) float s_buf[4][3][LEN];
  const int tid = threadIdx.x;
  const int wave = tid >> 6, lane = tid & 63;
  const int b = blockIdx.x >> 6;
  const int k = blockIdx.x & 63;
  const int orow0 = blockIdx.x * 32 + wave * 8;  // global OUTPUT row id
  const int i0 = orow0 & (LEN - 1);
  const long plane = (long)(orow0 & ~(LEN - 1)) * LEN;
  const int* srcb_full = src + b * LEN;

  // source rows for my 8 output rows
  int rs[8];
#pragma unroll
  for (int r = 0; r < 8; ++r) rs[r] = srcb_full[i0 + r];

  // column gather sources (dense-segment mapping, same as R8)
  int c0[4], c1[4];
#pragma unroll
  for (int kk = 0; kk < 4; ++kk) {
    c0[kk] = srcb_full[lane * 4 + kk];
    c1[kk] = srcb_full[256 + lane * 4 + kk];
  }

  float* op0 = out + plane + (long)i0 * LEN + lane * 4;

#define ISSUE(r, s) do {                                              \
    const float* gp = in + plane + (long)rs[r] * LEN + lane * 4;      \
    float* lp = &s_buf[wave][s][0];                                   \
    gload16(gp, lp);                                                  \
    gload16(gp + 256, lp + 256);                                      \
  } while (0)

#define WAITV(n) asm volatile("s_waitcnt vmcnt(" #n ")" ::: "memory")

#define GATHER(r, s) do {                                             \
    const float* myrow = &s_buf[wave][s][0];                          \
    f4 q0, q1;                                                        \
    q0.x = myrow[c0[0]]; q0.y = myrow[c0[1]];                         \
    q0.z = myrow[c0[2]]; q0.w = myrow[c0[3]];                         \
    q1.x = myrow[c1[0]]; q1.y = myrow[c1[1]];                         \
    q1.z = myrow[c1[2]]; q1.w = myrow[c1[3]];                         \
    f4* op = (f4*)(op0 + (long)(r) * LEN);                            \
    op[0] = q0;                                                       \
    *(f4*)((float*)op + 256) = q1;                                    \
  } while (0)

  // issue-order ledger (2 instrs per ISSUE, 2 per GATHER's stores):
  // L0 L1 | L2 W4 G0 | L3 W6 G1 | L4 W8 G2 | L5 W8 G3 | L6 W8 G4 |
  // L7 W8 G5 | W6 G6 | W4 G7      (W_n: ops newer than L_r == n)
  ISSUE(0, 0);
  ISSUE(1, 1);
  ISSUE(2, 2); WAITV(4); GATHER(0, 0);
  ISSUE(3, 0); WAITV(6); GATHER(1, 1);
  ISSUE(4, 1); WAITV(8); GATHER(2, 2);
  ISSUE(5, 2); WAITV(8); GATHER(3, 0);
  ISSUE(6, 0); WAITV(8); GATHER(4, 1);
  ISSUE(7, 1); WAITV(8); GATHER(5, 2);
               WAITV(6); GATHER(6, 0);
               WAITV(4); GATHER(7, 1);
#undef ISSUE
#undef WAITV
#undef GATHER

  // ---- fused x/v gather + trim for this (b, k); dense writes ----
  const int ml = ml_arr[b];
  {
    const float* xrow = xin + (long)((b << 6) + k) * LEN;
    float* orow = xout + (long)((b << 6) + k) * LEN;
    for (int p = tid; p < LEN; p += 256) {
      orow[p] = (p < ml) ? xrow[srcb_full[p]] : 0.0f;
    }
  }
  if (k < NCV) {
    const float* vrow = vin + (long)((b << 2) + k) * LEN;
    float* orow = vout + (long)((b << 2) + k) * LEN;
    for (int p = tid; p < LEN; p += 256) {
      orow[p] = (p < ml) ? vrow[srcb_full[p]] : 0.0f;
    }
  }
}

extern "C" void kernel_launch(void* const* d_in, const int* in_sizes, int n_in,
                              void* d_out, int out_size, void* d_ws, size_t ws_size,
                              hipStream_t stream) {
  const float* x  = (const float*)d_in[0];   // (64,64,512)
  const float* v  = (const float*)d_in[1];   // (64,4,512)
  const float* uu = (const float*)d_in[2];   // (64,4,512,512)
  const void*  mask = d_in[3];               // (64,1,512)

  float* out   = (float*)d_out;
  float* out_x = out;                        // 2,097,152
  float* out_v = out + 2097152;              // 131,072
  float* out_m = out + 2228224;              // 32,768
  float* out_u = out + 2260992;              // 67,108,864

  int* src = (int*)d_ws;                     // 64*512 ints
  int* dst = src + NB * LEN;                 // 64*512 ints
  int* ml  = dst + NB * LEN;                 // 64 ints

  build_perm<<<NB, LEN, 0, stream>>>(mask, src, dst, ml, out_m);

  uu_perm<<<(NB * NCU * LEN) / 32, 256, 0, stream>>>(
      uu, out_u, x, v, out_x, out_v, src, ml);
}

// Round 14
// 110.681 us; speedup vs baseline: 1.0599x; 1.0599x over previous
//
#include <hip/hip_runtime.h>
#include <stdint.h>

#define LEN 512
#define NB 64
#define NCX 64
#define NCV 4
#define NCU 4

typedef float f4 __attribute__((ext_vector_type(4)));

// ---------------- Threefry-2x32, 20 rounds, key = (0, 42) ----------------
__device__ __forceinline__ uint32_t rotl32(uint32_t v, int r) {
  return (v << r) | (v >> (32 - r));
}

__device__ __forceinline__ void threefry2x32_k042(uint32_t c0, uint32_t c1,
                                                  uint32_t& o0, uint32_t& o1) {
  const uint32_t ks0 = 0u, ks1 = 42u;
  const uint32_t ks2 = 0u ^ 42u ^ 0x1BD11BDAu;
  uint32_t x0 = c0 + ks0;
  uint32_t x1 = c1 + ks1;
#define TF_ROUND(R) { x0 += x1; x1 = rotl32(x1, R); x1 ^= x0; }
  TF_ROUND(13) TF_ROUND(15) TF_ROUND(26) TF_ROUND(6)
  x0 += ks1; x1 += ks2 + 1u;
  TF_ROUND(17) TF_ROUND(29) TF_ROUND(16) TF_ROUND(24)
  x0 += ks2; x1 += ks0 + 2u;
  TF_ROUND(13) TF_ROUND(15) TF_ROUND(26) TF_ROUND(6)
  x0 += ks0; x1 += ks1 + 3u;
  TF_ROUND(17) TF_ROUND(29) TF_ROUND(16) TF_ROUND(24)
  x0 += ks1; x1 += ks2 + 4u;
  TF_ROUND(13) TF_ROUND(15) TF_ROUND(26) TF_ROUND(6)
  x0 += ks2; x1 += ks0 + 5u;
#undef TF_ROUND
  o0 = x0; o1 = x1;
}

// ---------------- Single fused kernel ----------------
// Each block (b = blk>>6, k = blk&63) redundantly computes sample b's
// permutation in LDS (threefry + ballot compaction + packed-key rank scan,
// ~1us on an otherwise-idle VALU), then streams its 32 uu output rows
// (direction B: dense sequential writes, upfront f4 loads, wave-private
// LDS row, zero barriers in the row loop) and the fused x/v tail.
// No build_perm kernel, no launch gap, no global src/dst tables.
//
// perm semantics (matches jnp.argsort(-rand) stable ascending):
//   positions [0, n_inv): invalid slots ordered by rand DESC, ties idx ASC
//   positions [n_inv, L): valid slots in original index order
// Packed key: (23-bit mantissa << 9) | (511 - idx) -> rank = one unsigned cmp.
__global__ __launch_bounds__(256) void fused_trim(
    const float* __restrict__ in, float* __restrict__ out,
    const float* __restrict__ xin, const float* __restrict__ vin,
    float* __restrict__ xout, float* __restrict__ vout,
    float* __restrict__ mask_out, const void* __restrict__ mask) {
  __shared__ alignas(16) uint32_t s_pack[LEN];
  __shared__ int s_src[LEN];
  __shared__ float s_row[4][LEN];
  __shared__ int wsum[8];
  __shared__ int woff[9];

  const int tid = threadIdx.x;
  const int wave = tid >> 6, lane = tid & 63;
  const int blk = blockIdx.x;
  const int b = blk >> 6;                      // 64 blocks per batch sample
  const int k = blk & 63;

  // ================= perm phase (2 positions per thread) =================
  const int l0 = tid, l1 = tid + 256;
  const uint32_t w0 = ((const uint32_t*)mask)[0];
  bool valid0, valid1;
  if (w0 == 1u) {                              // int32 0/1
    valid0 = ((const int*)mask)[b * LEN + l0] != 0;
    valid1 = ((const int*)mask)[b * LEN + l1] != 0;
  } else if (w0 == 0x3F800000u) {              // float32 0.0/1.0
    valid0 = ((const float*)mask)[b * LEN + l0] != 0.0f;
    valid1 = ((const float*)mask)[b * LEN + l1] != 0.0f;
  } else {                                     // 1-byte bool
    valid0 = ((const unsigned char*)mask)[b * LEN + l0] != 0;
    valid1 = ((const unsigned char*)mask)[b * LEN + l1] != 0;
  }
  const bool inv0 = !valid0, inv1 = !valid1;

  uint32_t a, c, me0, me1;
  threefry2x32_k042(0u, (uint32_t)(b * LEN + l0), a, c);
  me0 = ((((a ^ c) >> 9) & 0x7FFFFFu) << 9) | (uint32_t)(511 - l0);
  threefry2x32_k042(0u, (uint32_t)(b * LEN + l1), a, c);
  me1 = ((((a ^ c) >> 9) & 0x7FFFFFu) << 9) | (uint32_t)(511 - l1);

  // order-preserving compaction: segment order = [h0w0..h0w3, h1w0..h1w3]
  const unsigned long long bal0 = __ballot(inv0);
  const unsigned long long bal1 = __ballot(inv1);
  const unsigned long long lmask = (1ull << lane) - 1ull;
  const int lower0 = __popcll(bal0 & lmask);
  const int lower1 = __popcll(bal1 & lmask);
  if (lane == 0) {
    wsum[wave] = __popcll(bal0);
    wsum[4 + wave] = __popcll(bal1);
  }
  __syncthreads();
  if (tid == 0) {
    int acc = 0;
    for (int w = 0; w < 8; ++w) { woff[w] = acc; acc += wsum[w]; }
    woff[8] = acc;
  }
  __syncthreads();
  const int n_inv = woff[8];
  const int ib0 = woff[wave] + lower0;         // # invalid with index < l0
  const int ib1 = woff[4 + wave] + lower1;     // # invalid with index < l1
  if (inv0) s_pack[ib0] = me0;
  if (inv1) s_pack[ib1] = me1;
  __syncthreads();

  int r0 = 0, r1 = 0;
  if (inv0 || inv1) {                          // one merged scan for both
    int j = 0;
    for (; j + 8 <= n_inv; j += 8) {
      const uint4 p0 = *(const uint4*)&s_pack[j];
      const uint4 p1 = *(const uint4*)&s_pack[j + 4];
      r0 += (int)(p0.x > me0) + (int)(p0.y > me0) + (int)(p0.z > me0) +
            (int)(p0.w > me0) + (int)(p1.x > me0) + (int)(p1.y > me0) +
            (int)(p1.z > me0) + (int)(p1.w > me0);
      r1 += (int)(p0.x > me1) + (int)(p0.y > me1) + (int)(p0.z > me1) +
            (int)(p0.w > me1) + (int)(p1.x > me1) + (int)(p1.y > me1) +
            (int)(p1.z > me1) + (int)(p1.w > me1);
    }
    for (; j < n_inv; ++j) {
      const uint32_t kj = s_pack[j];
      r0 += (int)(kj > me0);
      r1 += (int)(kj > me1);
    }
  }
  const int pos0 = inv0 ? r0 : n_inv + (l0 - ib0);
  const int pos1 = inv1 ? r1 : n_inv + (l1 - ib1);
  s_src[pos0] = l0;
  s_src[pos1] = l1;

  const int nv = LEN - n_inv;
  const int ml = nv < 1 ? 1 : nv;
  if (k == 0) {                                // one block per b writes mask_p
    mask_out[b * LEN + l0] = (l0 >= n_inv && l0 < ml) ? 1.0f : 0.0f;
    mask_out[b * LEN + l1] = (l1 >= n_inv && l1 < ml) ? 1.0f : 0.0f;
  }
  __syncthreads();                             // s_src complete

  // ================= uu streaming phase (R9 structure) =================
  const int orow0 = blk * 32 + wave * 8;       // global OUTPUT row id
  const int i0 = orow0 & (LEN - 1);            // output row within plane
  const long plane = (long)(orow0 & ~(LEN - 1)) * LEN;

  int rs[8];
#pragma unroll
  for (int r = 0; r < 8; ++r) rs[r] = s_src[i0 + r];

  // issue all 16 row loads upfront; each covers a dense 1KB segment
  f4 a0[8], a1[8];
#pragma unroll
  for (int r = 0; r < 8; ++r) {
    const float* ip = in + plane + (long)rs[r] * LEN + lane * 4;
    a0[r] = *(const f4*)(ip);
    a1[r] = *(const f4*)(ip + 256);
  }

  int c0[4], c1[4];
#pragma unroll
  for (int kk = 0; kk < 4; ++kk) {
    c0[kk] = s_src[lane * 4 + kk];
    c1[kk] = s_src[256 + lane * 4 + kk];
  }

  float* myrow = &s_row[wave][0];
  float* op0 = out + plane + (long)i0 * LEN + lane * 4;

#pragma unroll
  for (int r = 0; r < 8; ++r) {
    *(f4*)(myrow + lane * 4) = a0[r];          // dense 1KB LDS write
    *(f4*)(myrow + 256 + lane * 4) = a1[r];
    f4 q0, q1;
    q0.x = myrow[c0[0]]; q0.y = myrow[c0[1]]; q0.z = myrow[c0[2]]; q0.w = myrow[c0[3]];
    q1.x = myrow[c1[0]]; q1.y = myrow[c1[1]]; q1.z = myrow[c1[2]]; q1.w = myrow[c1[3]];
    f4* op = (f4*)(op0 + (long)r * LEN);
    op[0] = q0;                                // dense 1KB store (seg0)
    *(f4*)((float*)op + 256) = q1;             // dense 1KB store (seg1)
  }

  // ================= fused x/v gather + trim for this (b, k) =============
  {
    const float* xrow = xin + (long)((b << 6) + k) * LEN;
    float* orow = xout + (long)((b << 6) + k) * LEN;
    for (int p = tid; p < LEN; p += 256) {
      orow[p] = (p < ml) ? xrow[s_src[p]] : 0.0f;
    }
  }
  if (k < NCV) {
    const float* vrow = vin + (long)((b << 2) + k) * LEN;
    float* orow = vout + (long)((b << 2) + k) * LEN;
    for (int p = tid; p < LEN; p += 256) {
      orow[p] = (p < ml) ? vrow[s_src[p]] : 0.0f;
    }
  }
}

extern "C" void kernel_launch(void* const* d_in, const int* in_sizes, int n_in,
                              void* d_out, int out_size, void* d_ws, size_t ws_size,
                              hipStream_t stream) {
  const float* x  = (const float*)d_in[0];   // (64,64,512)
  const float* v  = (const float*)d_in[1];   // (64,4,512)
  const float* uu = (const float*)d_in[2];   // (64,4,512,512)
  const void*  mask = d_in[3];               // (64,1,512)

  float* out   = (float*)d_out;
  float* out_x = out;                        // 2,097,152
  float* out_v = out + 2097152;              // 131,072
  float* out_m = out + 2228224;              // 32,768
  float* out_u = out + 2260992;              // 67,108,864

  fused_trim<<<NB * NCU * LEN / 32, 256, 0, stream>>>(
      uu, out_u, x, v, out_x, out_v, out_m, mask);
}